// Round 1
// baseline (478.562 us; speedup 1.0000x reference)
//
#include <hip/hip_runtime.h>
#include <hip/hip_bf16.h>

#define N_NODES 4096
#define NFEAT   128
#define DIM     64
#define GHID    64
#define NEDGE   32768
#define NBATCH  32

typedef __attribute__((ext_vector_type(8))) short short8;
typedef __attribute__((ext_vector_type(4))) float f4;

__device__ __forceinline__ float sigf(float x) { return 1.0f / (1.0f + expf(-x)); }

// ---------------- setup kernels ----------------

__global__ void k_count(const int* __restrict__ eidx, int* cnt_src, int* cnt_dst) {
    int e = blockIdx.x * 256 + threadIdx.x;
    if (e < NEDGE) {
        atomicAdd(&cnt_src[eidx[e]], 1);
        atomicAdd(&cnt_dst[eidx[NEDGE + e]], 1);
    }
}

__global__ __launch_bounds__(1024) void k_scan(const int* __restrict__ cnt_src,
                                               const int* __restrict__ cnt_dst,
                                               int* csr_off, int* fill_ptr, float* invdeg) {
    __shared__ int part[1024];
    int t = threadIdx.x;
    int base = t * 4;
    int v0 = cnt_src[base], v1 = cnt_src[base + 1], v2 = cnt_src[base + 2], v3 = cnt_src[base + 3];
    int mysum = v0 + v1 + v2 + v3;
    part[t] = mysum;
    __syncthreads();
    for (int off = 1; off < 1024; off <<= 1) {
        int x = (t >= off) ? part[t - off] : 0;
        __syncthreads();
        part[t] += x;
        __syncthreads();
    }
    int excl = part[t] - mysum;
    csr_off[base] = excl;     fill_ptr[base] = excl;     excl += v0;
    csr_off[base + 1] = excl; fill_ptr[base + 1] = excl; excl += v1;
    csr_off[base + 2] = excl; fill_ptr[base + 2] = excl; excl += v2;
    csr_off[base + 3] = excl; fill_ptr[base + 3] = excl;
    if (t == 1023) csr_off[N_NODES] = part[1023];
    for (int n = t; n < N_NODES; n += 1024) {
        int d = cnt_dst[n];
        invdeg[n] = 1.0f / (float)(d > 0 ? d : 1);
    }
}

__global__ void k_fill(const int* __restrict__ eidx, const float* __restrict__ ea,
                       int* fill_ptr, int* csr_dst, float* csr_ea) {
    int e = blockIdx.x * 256 + threadIdx.x;
    if (e < NEDGE) {
        int s = eidx[e];
        int pos = atomicAdd(&fill_ptr[s], 1);
        csr_dst[pos] = eidx[NEDGE + e];
        csr_ea[pos] = ea[e];
    }
}

// transpose enn_W2[l][g][k][o] -> W2T[(l*64+g)][o][k] in bf16
__global__ __launch_bounds__(256) void k_w2t(const float* __restrict__ enn_W2,
                                             __hip_bfloat16* __restrict__ W2T) {
    __shared__ __hip_bfloat16 tile[64 * 65];
    size_t base = (size_t)blockIdx.x * 4096;
    int t = threadIdx.x;
    for (int i = t; i < 4096; i += 256) {
        int k = i >> 6, o = i & 63;
        tile[o * 65 + k] = __float2bfloat16(enn_W2[base + i]);
    }
    __syncthreads();
    for (int i = t; i < 4096; i += 256) {
        int o = i >> 6, k = i & 63;
        W2T[base + i] = tile[o * 65 + k];
    }
}

__global__ void k_batchrange(const int* __restrict__ bm, int* bstart, int* bend) {
    int n = blockIdx.x * 256 + threadIdx.x;
    if (n < N_NODES) {
        int b = bm[n];
        atomicMin(&bstart[b], n);
        atomicMax(&bend[b], n + 1);
    }
}

// ---------------- pre-MLP (3 layers fused) ----------------

__global__ __launch_bounds__(256) void k_premlp(const float* __restrict__ x,
        const float* __restrict__ W0, const float* __restrict__ b0,
        const float* __restrict__ W1, const float* __restrict__ b1,
        const float* __restrict__ W2, const float* __restrict__ b2,
        float* __restrict__ out) {
    __shared__ float xr[4][NFEAT];
    __shared__ float ha[4][DIM];
    __shared__ float hb[4][DIM];
    int t = threadIdx.x, w = t >> 6, j = t & 63;
    int n = blockIdx.x * 4 + w;
    xr[w][j] = x[(size_t)n * NFEAT + j];
    xr[w][64 + j] = x[(size_t)n * NFEAT + 64 + j];
    __syncthreads();
    float s = b0[j];
    #pragma unroll 8
    for (int k = 0; k < 128; ++k) s = fmaf(xr[w][k], W0[k * 64 + j], s);
    ha[w][j] = fmaxf(s, 0.f);
    __syncthreads();
    s = b1[j];
    #pragma unroll 8
    for (int k = 0; k < 64; ++k) s = fmaf(ha[w][k], W1[k * 64 + j], s);
    hb[w][j] = fmaxf(s, 0.f);
    __syncthreads();
    s = b2[j];
    #pragma unroll 8
    for (int k = 0; k < 64; ++k) s = fmaf(hb[w][k], W2[k * 64 + j], s);
    out[(size_t)n * 64 + j] = fmaxf(s, 0.f);
}

// ---------------- P = out @ W2 (MFMA bf16) ----------------
// P[n][g*64+o], W2T_l: [g][o][k] bf16 (B^T layout)

__global__ __launch_bounds__(256) void k_gemmP(const float* __restrict__ out,
        const __hip_bfloat16* __restrict__ W2T_l, __hip_bfloat16* __restrict__ P) {
    __shared__ __hip_bfloat16 A[64][72];  // pad 72 -> 2-way-max LDS conflicts
    int mtile = blockIdx.x, gchunk = blockIdx.y;
    int t = threadIdx.x;
    const float* Ain = out + (size_t)mtile * 64 * 64;
    for (int i = t; i < 4096; i += 256)
        A[i >> 6][i & 63] = __float2bfloat16(Ain[i]);
    __syncthreads();
    int wave = t >> 6, lane = t & 63;
    int laneM = lane & 15, quad = lane >> 4;
    int arow = wave * 16 + laneM;
    short8 a0 = *(const short8*)&A[arow][quad * 8];        // A[m=lane&15][k=quad*8+j], k chunk 0
    short8 a1 = *(const short8*)&A[arow][32 + quad * 8];   // k chunk 1
    #pragma unroll
    for (int gg = 0; gg < 8; ++gg) {
        int g = gchunk * 8 + gg;
        const __hip_bfloat16* Bt = W2T_l + (size_t)g * 4096;  // [o][k]
        #pragma unroll
        for (int sub = 0; sub < 4; ++sub) {
            int o0 = sub * 16;
            short8 b0v = *(const short8*)(Bt + (o0 + laneM) * 64 + quad * 8);
            short8 b1v = *(const short8*)(Bt + (o0 + laneM) * 64 + 32 + quad * 8);
            f4 acc = {0.f, 0.f, 0.f, 0.f};
            acc = __builtin_amdgcn_mfma_f32_16x16x32_bf16(a0, b0v, acc, 0, 0, 0);
            acc = __builtin_amdgcn_mfma_f32_16x16x32_bf16(a1, b1v, acc, 0, 0, 0);
            int rowg = mtile * 64 + wave * 16 + quad * 4;   // D: row=(lane>>4)*4+r
            int col = g * 64 + o0 + laneM;                  // D: col=lane&15
            #pragma unroll
            for (int r = 0; r < 4; ++r)
                P[(size_t)(rowg + r) * 4096 + col] = __float2bfloat16(acc[r]);
        }
    }
}

// BT[n][o] = sum_i out[n,i] * b2[i*64+o]
__global__ __launch_bounds__(256) void k_bterm(const float* __restrict__ out,
        const float* __restrict__ b2l, float* __restrict__ BT) {
    __shared__ float sh[4][64];
    int t = threadIdx.x, w = t >> 6, j = t & 63;
    int n = blockIdx.x * 4 + w;
    sh[w][j] = out[(size_t)n * 64 + j];
    __syncthreads();
    float s = 0.f;
    #pragma unroll 8
    for (int k = 0; k < 64; ++k) s = fmaf(sh[w][k], b2l[k * 64 + j], s);
    BT[(size_t)n * 64 + j] = s;
}

// ---------------- message + scatter ----------------
#define MSG_CHUNK 128

__global__ __launch_bounds__(256) void k_msg(const __hip_bfloat16* __restrict__ P,
        const float* __restrict__ BT, const int* __restrict__ csr_off,
        const int* __restrict__ csr_dst, const float* __restrict__ csr_ea,
        const float* __restrict__ invdeg, const float* __restrict__ W1l,
        const float* __restrict__ b1l, float* __restrict__ agg) {
    __shared__ float wlds[MSG_CHUNK][64];
    int t = threadIdx.x, wave = t >> 6, lane = t & 63;
    int n0 = blockIdx.x * 4;
    int n = n0 + wave;
    int bs = csr_off[n0], be = csr_off[n0 + 4];
    int ms = csr_off[n], me = csr_off[n + 1];
    float w1v = W1l[lane], b1v = b1l[lane];
    float preg[64];
    const __hip_bfloat16* Pn = P + (size_t)n * 4096;
    #pragma unroll
    for (int g = 0; g < 64; ++g) preg[g] = __bfloat162float(Pn[g * 64 + lane]);
    float bt = BT[(size_t)n * 64 + lane];
    for (int cs = bs; cs < be; cs += MSG_CHUNK) {
        int ccount = be - cs; if (ccount > MSG_CHUNK) ccount = MSG_CHUNK;
        __syncthreads();
        for (int si = wave; si < ccount; si += 4) {
            float ea = csr_ea[cs + si];
            wlds[si][lane] = fmaxf(fmaf(ea, w1v, b1v), 0.f);   // We1 (lane = g)
        }
        __syncthreads();
        int i0 = ms > cs ? ms : cs;
        int i1 = me < cs + ccount ? me : cs + ccount;
        for (int i = i0; i < i1; ++i) {
            int si = i - cs;
            int dst = csr_dst[i];
            float idg = invdeg[dst];
            float acc = bt;
            const float* wr = wlds[si];
            #pragma unroll
            for (int g = 0; g < 64; g += 4) {
                float4 wv = *(const float4*)(wr + g);
                acc = fmaf(wv.x, preg[g], acc);
                acc = fmaf(wv.y, preg[g + 1], acc);
                acc = fmaf(wv.z, preg[g + 2], acc);
                acc = fmaf(wv.w, preg[g + 3], acc);
            }
            atomicAdd(&agg[(size_t)dst * 64 + lane], acc * idg);
        }
    }
}

// ---------------- conv + GRU ----------------

__global__ __launch_bounds__(256) void k_gru(const float* __restrict__ out,
        const float* __restrict__ agg, const float* __restrict__ rootW,
        const float* __restrict__ convb, const float* __restrict__ Wih,
        const float* __restrict__ Whh, const float* __restrict__ bih,
        const float* __restrict__ bhh, float* __restrict__ outn) {
    __shared__ float sh[4][64], sc[4][64];
    int t = threadIdx.x, w = t >> 6, j = t & 63;
    int n = blockIdx.x * 4 + w;
    float hj = out[(size_t)n * 64 + j];
    sh[w][j] = hj;
    __syncthreads();
    float s = agg[(size_t)n * 64 + j] + convb[j];
    #pragma unroll 8
    for (int k = 0; k < 64; ++k) s = fmaf(sh[w][k], rootW[k * 64 + j], s);
    float conv = fmaxf(s, 0.f);
    sc[w][j] = conv;
    __syncthreads();
    float gir = bih[j], giz = bih[64 + j], gin = bih[128 + j];
    float ghr = bhh[j], ghz = bhh[64 + j], ghn = bhh[128 + j];
    #pragma unroll 4
    for (int k = 0; k < 64; ++k) {
        float c = sc[w][k], h = sh[w][k];
        gir = fmaf(c, Wih[k * 192 + j], gir);
        giz = fmaf(c, Wih[k * 192 + 64 + j], giz);
        gin = fmaf(c, Wih[k * 192 + 128 + j], gin);
        ghr = fmaf(h, Whh[k * 192 + j], ghr);
        ghz = fmaf(h, Whh[k * 192 + 64 + j], ghz);
        ghn = fmaf(h, Whh[k * 192 + 128 + j], ghn);
    }
    float r = sigf(gir + ghr);
    float z = sigf(giz + ghz);
    float nn = tanhf(gin + r * ghn);
    outn[(size_t)n * 64 + j] = (1.f - z) * nn + z * hj;
}

// ---------------- Set2Set (3 steps) + post-MLP, one block per batch ----------------

__global__ __launch_bounds__(256) void k_s2s_post(const float* __restrict__ out,
        const int* __restrict__ bstart, const int* __restrict__ bend,
        const float* __restrict__ Wih, const float* __restrict__ Whh,
        const float* __restrict__ bih, const float* __restrict__ bhh,
        const float* __restrict__ pW0, const float* __restrict__ pb0,
        const float* __restrict__ pW1, const float* __restrict__ pb1,
        const float* __restrict__ pW2, const float* __restrict__ pb2,
        const float* __restrict__ pW3, const float* __restrict__ pb3,
        float* __restrict__ y) {
    __shared__ float qs[128], hh[64], cc[64], gates[256], red[256];
    __shared__ float ebuf[1024];
    __shared__ float rpart[4][64];
    int t = threadIdx.x, wave = t >> 6, lane = t & 63;
    int b = blockIdx.x;
    int s0 = bstart[b], e0 = bend[b];
    int cnt = e0 - s0;
    if (cnt < 0) cnt = 0;
    if (cnt > 1024) cnt = 1024;
    if (t < 128) qs[t] = 0.f;
    if (t < 64) { hh[t] = 0.f; cc[t] = 0.f; }
    __syncthreads();
    for (int step = 0; step < 3; ++step) {
        float g = bih[t] + bhh[t];
        #pragma unroll 4
        for (int k = 0; k < 128; ++k) g = fmaf(qs[k], Wih[k * 256 + t], g);
        #pragma unroll 4
        for (int k = 0; k < 64; ++k) g = fmaf(hh[k], Whh[k * 256 + t], g);
        gates[t] = g;
        __syncthreads();
        if (t < 64) {
            float cn = sigf(gates[64 + t]) * cc[t] + sigf(gates[t]) * tanhf(gates[128 + t]);
            cc[t] = cn;
            hh[t] = sigf(gates[192 + t]) * tanhf(cn);
        }
        __syncthreads();
        for (int idx = wave; idx < cnt; idx += 4) {
            float p = out[(size_t)(s0 + idx) * 64 + lane] * hh[lane];
            #pragma unroll
            for (int off = 32; off > 0; off >>= 1) p += __shfl_down(p, off, 64);
            if (lane == 0) ebuf[idx] = p;
        }
        __syncthreads();
        float lm = -3.0e38f;
        for (int i = t; i < cnt; i += 256) lm = fmaxf(lm, ebuf[i]);
        red[t] = lm;
        __syncthreads();
        for (int off = 128; off > 0; off >>= 1) {
            if (t < off) red[t] = fmaxf(red[t], red[t + off]);
            __syncthreads();
        }
        float m = red[0];
        __syncthreads();
        float ls = 0.f;
        for (int i = t; i < cnt; i += 256) {
            float av = expf(ebuf[i] - m);
            ebuf[i] = av;
            ls += av;
        }
        red[t] = ls;
        __syncthreads();
        for (int off = 128; off > 0; off >>= 1) {
            if (t < off) red[t] += red[t + off];
            __syncthreads();
        }
        float inv = (cnt > 0) ? 1.f / red[0] : 0.f;
        __syncthreads();
        float r = 0.f;
        for (int idx = wave; idx < cnt; idx += 4)
            r = fmaf(ebuf[idx], out[(size_t)(s0 + idx) * 64 + lane], r);
        rpart[wave][lane] = r;
        __syncthreads();
        if (t < 64) {
            qs[64 + t] = (rpart[0][t] + rpart[1][t] + rpart[2][t] + rpart[3][t]) * inv;
            qs[t] = hh[t];
        }
        __syncthreads();
    }
    // post-MLP
    if (t < 64) {
        float s = pb0[t];
        #pragma unroll 4
        for (int k = 0; k < 128; ++k) s = fmaf(qs[k], pW0[k * 64 + t], s);
        red[t] = fmaxf(s, 0.f);
    }
    __syncthreads();
    float h1v = 0.f;
    if (t < 64) {
        float s = pb1[t];
        #pragma unroll 4
        for (int k = 0; k < 64; ++k) s = fmaf(red[k], pW1[k * 64 + t], s);
        h1v = fmaxf(s, 0.f);
    }
    __syncthreads();
    if (t < 64) red[t] = h1v;
    __syncthreads();
    if (t < 64) {
        float s = pb2[t];
        #pragma unroll 4
        for (int k = 0; k < 64; ++k) s = fmaf(red[k], pW2[k * 64 + t], s);
        gates[t] = fmaxf(s, 0.f) * pW3[t];
    }
    __syncthreads();
    if (t == 0) {
        float yy = pb3[0];
        for (int k = 0; k < 64; ++k) yy += gates[k];
        y[b] = yy;
    }
}

// ---------------- host ----------------

extern "C" void kernel_launch(void* const* d_in, const int* in_sizes, int n_in,
                              void* d_out, int out_size, void* d_ws, size_t ws_size,
                              hipStream_t stream) {
    const float* x         = (const float*)d_in[0];
    const float* edge_attr = (const float*)d_in[1];
    const int*   edge_idx  = (const int*)d_in[2];
    const int*   batch_map = (const int*)d_in[3];
    const float* pre_W0 = (const float*)d_in[4];
    const float* pre_b0 = (const float*)d_in[5];
    const float* pre_W1 = (const float*)d_in[6];
    const float* pre_b1 = (const float*)d_in[7];
    const float* pre_W2 = (const float*)d_in[8];
    const float* pre_b2 = (const float*)d_in[9];
    const float* enn_W1 = (const float*)d_in[10];
    const float* enn_b1 = (const float*)d_in[11];
    const float* enn_W2 = (const float*)d_in[12];
    const float* enn_b2 = (const float*)d_in[13];
    const float* root_W = (const float*)d_in[14];
    const float* conv_b = (const float*)d_in[15];
    const float* gru_Wih = (const float*)d_in[16];
    const float* gru_Whh = (const float*)d_in[17];
    const float* gru_bih = (const float*)d_in[18];
    const float* gru_bhh = (const float*)d_in[19];
    const float* s2s_Wih = (const float*)d_in[20];
    const float* s2s_Whh = (const float*)d_in[21];
    const float* s2s_bih = (const float*)d_in[22];
    const float* s2s_bhh = (const float*)d_in[23];
    const float* post_W0 = (const float*)d_in[24];
    const float* post_b0 = (const float*)d_in[25];
    const float* post_W1 = (const float*)d_in[26];
    const float* post_b1 = (const float*)d_in[27];
    const float* post_W2 = (const float*)d_in[28];
    const float* post_b2 = (const float*)d_in[29];
    const float* post_W3 = (const float*)d_in[30];
    const float* post_b3 = (const float*)d_in[31];
    float* yout = (float*)d_out;

    char* p = (char*)d_ws;
    auto take = [&](size_t bytes) -> char* {
        char* r = p;
        p += (bytes + 255) & ~(size_t)255;
        return r;
    };
    float* outA = (float*)take((size_t)N_NODES * 64 * 4);
    float* outB = (float*)take((size_t)N_NODES * 64 * 4);
    __hip_bfloat16* P = (__hip_bfloat16*)take((size_t)N_NODES * 4096 * 2);
    float* BT  = (float*)take((size_t)N_NODES * 64 * 4);
    float* agg = (float*)take((size_t)N_NODES * 64 * 4);
    __hip_bfloat16* W2T = (__hip_bfloat16*)take((size_t)3 * 64 * 4096 * 2);
    int* csr_off  = (int*)take((size_t)(N_NODES + 1) * 4);
    int* fill_ptr = (int*)take((size_t)N_NODES * 4);
    int* cnt_src  = (int*)take((size_t)N_NODES * 4);
    int* cnt_dst  = (int*)take((size_t)N_NODES * 4);
    float* invdeg = (float*)take((size_t)N_NODES * 4);
    int* csr_dst  = (int*)take((size_t)NEDGE * 4);
    float* csr_ea = (float*)take((size_t)NEDGE * 4);
    int* bstart   = (int*)take((size_t)NBATCH * 4);
    int* bend     = (int*)take((size_t)NBATCH * 4);

    hipMemsetAsync(cnt_src, 0, (size_t)N_NODES * 4, stream);
    hipMemsetAsync(cnt_dst, 0, (size_t)N_NODES * 4, stream);
    hipMemsetAsync(bstart, 0x7F, (size_t)NBATCH * 4, stream);
    hipMemsetAsync(bend, 0, (size_t)NBATCH * 4, stream);

    k_count<<<NEDGE / 256, 256, 0, stream>>>(edge_idx, cnt_src, cnt_dst);
    k_scan<<<1, 1024, 0, stream>>>(cnt_src, cnt_dst, csr_off, fill_ptr, invdeg);
    k_fill<<<NEDGE / 256, 256, 0, stream>>>(edge_idx, edge_attr, fill_ptr, csr_dst, csr_ea);
    k_w2t<<<192, 256, 0, stream>>>(enn_W2, W2T);
    k_batchrange<<<N_NODES / 256, 256, 0, stream>>>(batch_map, bstart, bend);
    k_premlp<<<N_NODES / 4, 256, 0, stream>>>(x, pre_W0, pre_b0, pre_W1, pre_b1,
                                              pre_W2, pre_b2, outA);

    float* cur = outA;
    float* nxt = outB;
    for (int l = 0; l < 3; ++l) {
        k_gemmP<<<dim3(64, 8), 256, 0, stream>>>(cur, W2T + (size_t)l * 64 * 4096, P);
        k_bterm<<<N_NODES / 4, 256, 0, stream>>>(cur, enn_b2 + (size_t)l * 4096, BT);
        hipMemsetAsync(agg, 0, (size_t)N_NODES * 64 * 4, stream);
        k_msg<<<N_NODES / 4, 256, 0, stream>>>(P, BT, csr_off, csr_dst, csr_ea, invdeg,
                                               enn_W1 + l * 64, enn_b1 + l * 64, agg);
        k_gru<<<N_NODES / 4, 256, 0, stream>>>(cur, agg, root_W + l * 4096, conv_b + l * 64,
                                               gru_Wih + l * 64 * 192, gru_Whh + l * 64 * 192,
                                               gru_bih + l * 192, gru_bhh + l * 192, nxt);
        float* tmp = cur; cur = nxt; nxt = tmp;
    }
    k_s2s_post<<<NBATCH, 256, 0, stream>>>(cur, bstart, bend, s2s_Wih, s2s_Whh, s2s_bih,
                                           s2s_bhh, post_W0, post_b0, post_W1, post_b1,
                                           post_W2, post_b2, post_W3, post_b3, yout);
}

// Round 2
// 429.511 us; speedup vs baseline: 1.1142x; 1.1142x over previous
//
#include <hip/hip_runtime.h>
#include <hip/hip_bf16.h>

#define N_NODES 4096
#define NFEAT   128
#define DIM     64
#define GHID    64
#define NEDGE   32768
#define NBATCH  32

typedef __attribute__((ext_vector_type(8))) short short8;
typedef __attribute__((ext_vector_type(4))) float f4;

__device__ __forceinline__ float sigf(float x) { return 1.0f / (1.0f + expf(-x)); }

// ---------------- setup kernels ----------------

// zero counters + batch ranges (d_ws is poisoned 0xAA before every launch)
__global__ __launch_bounds__(256) void k_init(int* cnt_src, int* cnt_dst,
                                              int* bstart, int* bend) {
    int i = blockIdx.x * 256 + threadIdx.x;
    if (i < N_NODES) cnt_src[i] = 0;
    else if (i < 2 * N_NODES) cnt_dst[i - N_NODES] = 0;
    if (i < NBATCH) { bstart[i] = 0x7FFFFFFF; bend[i] = 0; }
}

__global__ void k_count(const int* __restrict__ eidx, const int* __restrict__ bm,
                        int* cnt_src, int* cnt_dst, int* bstart, int* bend) {
    int e = blockIdx.x * 256 + threadIdx.x;
    if (e < NEDGE) {
        atomicAdd(&cnt_src[eidx[e]], 1);
        atomicAdd(&cnt_dst[eidx[NEDGE + e]], 1);
    }
    if (e < N_NODES) {
        int b = bm[e];
        atomicMin(&bstart[b], e);
        atomicMax(&bend[b], e + 1);
    }
}

__global__ __launch_bounds__(1024) void k_scan(const int* __restrict__ cnt_src,
                                               const int* __restrict__ cnt_dst,
                                               int* csr_off, int* fill_ptr, float* invdeg) {
    __shared__ int part[1024];
    int t = threadIdx.x;
    int base = t * 4;
    int v0 = cnt_src[base], v1 = cnt_src[base + 1], v2 = cnt_src[base + 2], v3 = cnt_src[base + 3];
    int mysum = v0 + v1 + v2 + v3;
    part[t] = mysum;
    __syncthreads();
    for (int off = 1; off < 1024; off <<= 1) {
        int x = (t >= off) ? part[t - off] : 0;
        __syncthreads();
        part[t] += x;
        __syncthreads();
    }
    int excl = part[t] - mysum;
    csr_off[base] = excl;     fill_ptr[base] = excl;     excl += v0;
    csr_off[base + 1] = excl; fill_ptr[base + 1] = excl; excl += v1;
    csr_off[base + 2] = excl; fill_ptr[base + 2] = excl; excl += v2;
    csr_off[base + 3] = excl; fill_ptr[base + 3] = excl;
    if (t == 1023) csr_off[N_NODES] = part[1023];
    for (int n = t; n < N_NODES; n += 1024) {
        int d = cnt_dst[n];
        invdeg[n] = 1.0f / (float)(d > 0 ? d : 1);
    }
}

__global__ void k_fill(const int* __restrict__ eidx, const float* __restrict__ ea,
                       int* fill_ptr, int* csr_dst, float* csr_ea) {
    int e = blockIdx.x * 256 + threadIdx.x;
    if (e < NEDGE) {
        int s = eidx[e];
        int pos = atomicAdd(&fill_ptr[s], 1);
        csr_dst[pos] = eidx[NEDGE + e];
        csr_ea[pos] = ea[e];
    }
}

// transpose enn_W2[l][g][k][o] -> W2T[(l*64+g)][o][k] in bf16
__global__ __launch_bounds__(256) void k_w2t(const float* __restrict__ enn_W2,
                                             __hip_bfloat16* __restrict__ W2T) {
    __shared__ __hip_bfloat16 tile[64 * 65];
    size_t base = (size_t)blockIdx.x * 4096;
    int t = threadIdx.x;
    for (int i = t; i < 4096; i += 256) {
        int k = i >> 6, o = i & 63;
        tile[o * 65 + k] = __float2bfloat16(enn_W2[base + i]);
    }
    __syncthreads();
    for (int i = t; i < 4096; i += 256) {
        int o = i >> 6, k = i & 63;
        W2T[base + i] = tile[o * 65 + k];
    }
}

// ---------------- pre-MLP (3 layers fused) ----------------

__global__ __launch_bounds__(256) void k_premlp(const float* __restrict__ x,
        const float* __restrict__ W0, const float* __restrict__ b0,
        const float* __restrict__ W1, const float* __restrict__ b1,
        const float* __restrict__ W2, const float* __restrict__ b2,
        float* __restrict__ out) {
    __shared__ float xr[4][NFEAT];
    __shared__ float ha[4][DIM];
    __shared__ float hb[4][DIM];
    int t = threadIdx.x, w = t >> 6, j = t & 63;
    int n = blockIdx.x * 4 + w;
    xr[w][j] = x[(size_t)n * NFEAT + j];
    xr[w][64 + j] = x[(size_t)n * NFEAT + 64 + j];
    __syncthreads();
    float s = b0[j];
    #pragma unroll 8
    for (int k = 0; k < 128; ++k) s = fmaf(xr[w][k], W0[k * 64 + j], s);
    ha[w][j] = fmaxf(s, 0.f);
    __syncthreads();
    s = b1[j];
    #pragma unroll 8
    for (int k = 0; k < 64; ++k) s = fmaf(ha[w][k], W1[k * 64 + j], s);
    hb[w][j] = fmaxf(s, 0.f);
    __syncthreads();
    s = b2[j];
    #pragma unroll 8
    for (int k = 0; k < 64; ++k) s = fmaf(hb[w][k], W2[k * 64 + j], s);
    out[(size_t)n * 64 + j] = fmaxf(s, 0.f);
}

// ---------------- P = out @ W2 (MFMA bf16) ----------------
// P[n][g*64+o], W2T_l: [g][o][k] bf16 (B^T layout)

__global__ __launch_bounds__(256) void k_gemmP(const float* __restrict__ out,
        const __hip_bfloat16* __restrict__ W2T_l, __hip_bfloat16* __restrict__ P) {
    __shared__ __hip_bfloat16 A[64][72];
    int mtile = blockIdx.x, gchunk = blockIdx.y;
    int t = threadIdx.x;
    const float* Ain = out + (size_t)mtile * 64 * 64;
    for (int i = t; i < 4096; i += 256)
        A[i >> 6][i & 63] = __float2bfloat16(Ain[i]);
    __syncthreads();
    int wave = t >> 6, lane = t & 63;
    int laneM = lane & 15, quad = lane >> 4;
    int arow = wave * 16 + laneM;
    short8 a0 = *(const short8*)&A[arow][quad * 8];
    short8 a1 = *(const short8*)&A[arow][32 + quad * 8];
    #pragma unroll
    for (int gg = 0; gg < 8; ++gg) {
        int g = gchunk * 8 + gg;
        const __hip_bfloat16* Bt = W2T_l + (size_t)g * 4096;  // [o][k]
        #pragma unroll
        for (int sub = 0; sub < 4; ++sub) {
            int o0 = sub * 16;
            short8 b0v = *(const short8*)(Bt + (o0 + laneM) * 64 + quad * 8);
            short8 b1v = *(const short8*)(Bt + (o0 + laneM) * 64 + 32 + quad * 8);
            f4 acc = {0.f, 0.f, 0.f, 0.f};
            acc = __builtin_amdgcn_mfma_f32_16x16x32_bf16(a0, b0v, acc, 0, 0, 0);
            acc = __builtin_amdgcn_mfma_f32_16x16x32_bf16(a1, b1v, acc, 0, 0, 0);
            int rowg = mtile * 64 + wave * 16 + quad * 4;   // D: row=(lane>>4)*4+r
            int col = g * 64 + o0 + laneM;                  // D: col=lane&15
            #pragma unroll
            for (int r = 0; r < 4; ++r)
                P[(size_t)(rowg + r) * 4096 + col] = __float2bfloat16(acc[r]);
        }
    }
}

// BT[n][o] = sum_i out[n,i] * b2[i*64+o]; also zero-initializes agg for k_msg
__global__ __launch_bounds__(256) void k_bterm(const float* __restrict__ out,
        const float* __restrict__ b2l, float* __restrict__ BT, float* __restrict__ agg) {
    __shared__ float sh[4][64];
    int t = threadIdx.x, w = t >> 6, j = t & 63;
    int n = blockIdx.x * 4 + w;
    sh[w][j] = out[(size_t)n * 64 + j];
    agg[(size_t)n * 64 + j] = 0.f;
    __syncthreads();
    float s = 0.f;
    #pragma unroll 8
    for (int k = 0; k < 64; ++k) s = fmaf(sh[w][k], b2l[k * 64 + j], s);
    BT[(size_t)n * 64 + j] = s;
}

// ---------------- message + scatter ----------------
#define MSG_CHUNK 128

// __launch_bounds__(256,2): allow up to 256 VGPRs so preg[64] stays in registers
// (default heuristic allocated 60 VGPRs -> preg spilled to scratch -> 40ms dispatch)
__global__ __launch_bounds__(256, 2) void k_msg(const __hip_bfloat16* __restrict__ P,
        const float* __restrict__ BT, const int* __restrict__ csr_off,
        const int* __restrict__ csr_dst, const float* __restrict__ csr_ea,
        const float* __restrict__ invdeg, const float* __restrict__ W1l,
        const float* __restrict__ b1l, float* __restrict__ agg) {
    __shared__ float wlds[MSG_CHUNK][64];
    int t = threadIdx.x, wave = t >> 6, lane = t & 63;
    int n0 = blockIdx.x * 4;
    int n = n0 + wave;
    int bs = csr_off[n0], be = csr_off[n0 + 4];
    int ms = csr_off[n], me = csr_off[n + 1];
    float w1v = W1l[lane], b1v = b1l[lane];
    float preg[64];
    const __hip_bfloat16* Pn = P + (size_t)n * 4096;
    #pragma unroll
    for (int g = 0; g < 64; ++g) preg[g] = __bfloat162float(Pn[g * 64 + lane]);
    float bt = BT[(size_t)n * 64 + lane];
    for (int cs = bs; cs < be; cs += MSG_CHUNK) {
        int ccount = be - cs; if (ccount > MSG_CHUNK) ccount = MSG_CHUNK;
        __syncthreads();
        for (int si = wave; si < ccount; si += 4) {
            float ea = csr_ea[cs + si];
            wlds[si][lane] = fmaxf(fmaf(ea, w1v, b1v), 0.f);   // We1 (lane = g)
        }
        __syncthreads();
        int i0 = ms > cs ? ms : cs;
        int i1 = me < cs + ccount ? me : cs + ccount;
        for (int i = i0; i < i1; ++i) {
            int si = i - cs;
            int dst = csr_dst[i];
            float idg = invdeg[dst];
            float acc = bt;
            const float* wr = wlds[si];
            #pragma unroll
            for (int g = 0; g < 64; g += 4) {
                float4 wv = *(const float4*)(wr + g);
                acc = fmaf(wv.x, preg[g], acc);
                acc = fmaf(wv.y, preg[g + 1], acc);
                acc = fmaf(wv.z, preg[g + 2], acc);
                acc = fmaf(wv.w, preg[g + 3], acc);
            }
            atomicAdd(&agg[(size_t)dst * 64 + lane], acc * idg);
        }
    }
}

// ---------------- conv + GRU ----------------

__global__ __launch_bounds__(256) void k_gru(const float* __restrict__ out,
        const float* __restrict__ agg, const float* __restrict__ rootW,
        const float* __restrict__ convb, const float* __restrict__ Wih,
        const float* __restrict__ Whh, const float* __restrict__ bih,
        const float* __restrict__ bhh, float* __restrict__ outn) {
    __shared__ float sh[4][64], sc[4][64];
    int t = threadIdx.x, w = t >> 6, j = t & 63;
    int n = blockIdx.x * 4 + w;
    float hj = out[(size_t)n * 64 + j];
    sh[w][j] = hj;
    __syncthreads();
    float s = agg[(size_t)n * 64 + j] + convb[j];
    #pragma unroll 8
    for (int k = 0; k < 64; ++k) s = fmaf(sh[w][k], rootW[k * 64 + j], s);
    float conv = fmaxf(s, 0.f);
    sc[w][j] = conv;
    __syncthreads();
    float gir = bih[j], giz = bih[64 + j], gin = bih[128 + j];
    float ghr = bhh[j], ghz = bhh[64 + j], ghn = bhh[128 + j];
    #pragma unroll 4
    for (int k = 0; k < 64; ++k) {
        float c = sc[w][k], h = sh[w][k];
        gir = fmaf(c, Wih[k * 192 + j], gir);
        giz = fmaf(c, Wih[k * 192 + 64 + j], giz);
        gin = fmaf(c, Wih[k * 192 + 128 + j], gin);
        ghr = fmaf(h, Whh[k * 192 + j], ghr);
        ghz = fmaf(h, Whh[k * 192 + 64 + j], ghz);
        ghn = fmaf(h, Whh[k * 192 + 128 + j], ghn);
    }
    float r = sigf(gir + ghr);
    float z = sigf(giz + ghz);
    float nn = tanhf(gin + r * ghn);
    outn[(size_t)n * 64 + j] = (1.f - z) * nn + z * hj;
}

// ---------------- Set2Set (3 steps) + post-MLP, one block (1024 thr) per batch ----------------

__global__ __launch_bounds__(1024) void k_s2s_post(const float* __restrict__ out,
        const int* __restrict__ bstart, const int* __restrict__ bend,
        const float* __restrict__ Wih, const float* __restrict__ Whh,
        const float* __restrict__ bih, const float* __restrict__ bhh,
        const float* __restrict__ pW0, const float* __restrict__ pb0,
        const float* __restrict__ pW1, const float* __restrict__ pb1,
        const float* __restrict__ pW2, const float* __restrict__ pb2,
        const float* __restrict__ pW3, const float* __restrict__ pb3,
        float* __restrict__ y) {
    __shared__ float qs[128], hh[64], cc[64], gates[256];
    __shared__ float ebuf[1024];
    __shared__ float redw[16];
    __shared__ float rpart[16][64];
    __shared__ float smax, sinv;
    __shared__ float tmp64[64];
    int t = threadIdx.x, wave = t >> 6, lane = t & 63;
    int b = blockIdx.x;
    int s0 = bstart[b], e0 = bend[b];
    int cnt = e0 - s0;
    if (cnt < 0) cnt = 0;
    if (cnt > 1024) cnt = 1024;
    if (t < 128) qs[t] = 0.f;
    if (t < 64) { hh[t] = 0.f; cc[t] = 0.f; }
    __syncthreads();
    for (int step = 0; step < 3; ++step) {
        if (t < 256) {
            float g = bih[t] + bhh[t];
            #pragma unroll 4
            for (int k = 0; k < 128; ++k) g = fmaf(qs[k], Wih[k * 256 + t], g);
            #pragma unroll 4
            for (int k = 0; k < 64; ++k) g = fmaf(hh[k], Whh[k * 256 + t], g);
            gates[t] = g;
        }
        __syncthreads();
        if (t < 64) {
            float cn = sigf(gates[64 + t]) * cc[t] + sigf(gates[t]) * tanhf(gates[128 + t]);
            cc[t] = cn;
            hh[t] = sigf(gates[192 + t]) * tanhf(cn);
        }
        __syncthreads();
        float hv = hh[lane];
        for (int idx = wave; idx < cnt; idx += 16) {
            float p = out[(size_t)(s0 + idx) * 64 + lane] * hv;
            #pragma unroll
            for (int off = 32; off > 0; off >>= 1) p += __shfl_down(p, off, 64);
            if (lane == 0) ebuf[idx] = p;
        }
        __syncthreads();
        // max over ebuf[0..cnt): one element per thread
        float lm = (t < cnt) ? ebuf[t] : -3.0e38f;
        #pragma unroll
        for (int off = 32; off > 0; off >>= 1) lm = fmaxf(lm, __shfl_down(lm, off, 64));
        if (lane == 0) redw[wave] = lm;
        __syncthreads();
        if (t == 0) {
            float m = redw[0];
            #pragma unroll
            for (int w2 = 1; w2 < 16; ++w2) m = fmaxf(m, redw[w2]);
            smax = m;
        }
        __syncthreads();
        float m = smax;
        float av = 0.f;
        if (t < cnt) {
            av = expf(ebuf[t] - m);
            ebuf[t] = av;
        }
        float ls = av;
        #pragma unroll
        for (int off = 32; off > 0; off >>= 1) ls += __shfl_down(ls, off, 64);
        if (lane == 0) redw[wave] = ls;
        __syncthreads();
        if (t == 0) {
            float s = 0.f;
            #pragma unroll
            for (int w2 = 0; w2 < 16; ++w2) s += redw[w2];
            sinv = (cnt > 0) ? 1.f / s : 0.f;
        }
        __syncthreads();
        float inv = sinv;
        float r = 0.f;
        for (int idx = wave; idx < cnt; idx += 16)
            r = fmaf(ebuf[idx], out[(size_t)(s0 + idx) * 64 + lane], r);
        rpart[wave][lane] = r;
        __syncthreads();
        if (t < 64) {
            float s = 0.f;
            #pragma unroll
            for (int w2 = 0; w2 < 16; ++w2) s += rpart[w2][t];
            qs[64 + t] = s * inv;
            qs[t] = hh[t];
        }
        __syncthreads();
    }
    // post-MLP
    if (t < 64) {
        float s = pb0[t];
        #pragma unroll 4
        for (int k = 0; k < 128; ++k) s = fmaf(qs[k], pW0[k * 64 + t], s);
        tmp64[t] = fmaxf(s, 0.f);
    }
    __syncthreads();
    float h1v = 0.f;
    if (t < 64) {
        float s = pb1[t];
        #pragma unroll 4
        for (int k = 0; k < 64; ++k) s = fmaf(tmp64[k], pW1[k * 64 + t], s);
        h1v = fmaxf(s, 0.f);
    }
    __syncthreads();
    if (t < 64) tmp64[t] = h1v;
    __syncthreads();
    if (t < 64) {
        float s = pb2[t];
        #pragma unroll 4
        for (int k = 0; k < 64; ++k) s = fmaf(tmp64[k], pW2[k * 64 + t], s);
        gates[t] = fmaxf(s, 0.f) * pW3[t];
    }
    __syncthreads();
    if (t == 0) {
        float yy = pb3[0];
        for (int k = 0; k < 64; ++k) yy += gates[k];
        y[b] = yy;
    }
}

// ---------------- host ----------------

extern "C" void kernel_launch(void* const* d_in, const int* in_sizes, int n_in,
                              void* d_out, int out_size, void* d_ws, size_t ws_size,
                              hipStream_t stream) {
    const float* x         = (const float*)d_in[0];
    const float* edge_attr = (const float*)d_in[1];
    const int*   edge_idx  = (const int*)d_in[2];
    const int*   batch_map = (const int*)d_in[3];
    const float* pre_W0 = (const float*)d_in[4];
    const float* pre_b0 = (const float*)d_in[5];
    const float* pre_W1 = (const float*)d_in[6];
    const float* pre_b1 = (const float*)d_in[7];
    const float* pre_W2 = (const float*)d_in[8];
    const float* pre_b2 = (const float*)d_in[9];
    const float* enn_W1 = (const float*)d_in[10];
    const float* enn_b1 = (const float*)d_in[11];
    const float* enn_W2 = (const float*)d_in[12];
    const float* enn_b2 = (const float*)d_in[13];
    const float* root_W = (const float*)d_in[14];
    const float* conv_b = (const float*)d_in[15];
    const float* gru_Wih = (const float*)d_in[16];
    const float* gru_Whh = (const float*)d_in[17];
    const float* gru_bih = (const float*)d_in[18];
    const float* gru_bhh = (const float*)d_in[19];
    const float* s2s_Wih = (const float*)d_in[20];
    const float* s2s_Whh = (const float*)d_in[21];
    const float* s2s_bih = (const float*)d_in[22];
    const float* s2s_bhh = (const float*)d_in[23];
    const float* post_W0 = (const float*)d_in[24];
    const float* post_b0 = (const float*)d_in[25];
    const float* post_W1 = (const float*)d_in[26];
    const float* post_b1 = (const float*)d_in[27];
    const float* post_W2 = (const float*)d_in[28];
    const float* post_b2 = (const float*)d_in[29];
    const float* post_W3 = (const float*)d_in[30];
    const float* post_b3 = (const float*)d_in[31];
    float* yout = (float*)d_out;

    char* p = (char*)d_ws;
    auto take = [&](size_t bytes) -> char* {
        char* r = p;
        p += (bytes + 255) & ~(size_t)255;
        return r;
    };
    float* outA = (float*)take((size_t)N_NODES * 64 * 4);
    float* outB = (float*)take((size_t)N_NODES * 64 * 4);
    __hip_bfloat16* P = (__hip_bfloat16*)take((size_t)N_NODES * 4096 * 2);
    float* BT  = (float*)take((size_t)N_NODES * 64 * 4);
    float* agg = (float*)take((size_t)N_NODES * 64 * 4);
    __hip_bfloat16* W2T = (__hip_bfloat16*)take((size_t)3 * 64 * 4096 * 2);
    int* csr_off  = (int*)take((size_t)(N_NODES + 1) * 4);
    int* fill_ptr = (int*)take((size_t)N_NODES * 4);
    int* cnt_src  = (int*)take((size_t)N_NODES * 4);
    int* cnt_dst  = (int*)take((size_t)N_NODES * 4);
    float* invdeg = (float*)take((size_t)N_NODES * 4);
    int* csr_dst  = (int*)take((size_t)NEDGE * 4);
    float* csr_ea = (float*)take((size_t)NEDGE * 4);
    int* bstart   = (int*)take((size_t)NBATCH * 4);
    int* bend     = (int*)take((size_t)NBATCH * 4);

    k_init<<<(2 * N_NODES) / 256, 256, 0, stream>>>(cnt_src, cnt_dst, bstart, bend);
    k_count<<<NEDGE / 256, 256, 0, stream>>>(edge_idx, batch_map, cnt_src, cnt_dst,
                                             bstart, bend);
    k_scan<<<1, 1024, 0, stream>>>(cnt_src, cnt_dst, csr_off, fill_ptr, invdeg);
    k_fill<<<NEDGE / 256, 256, 0, stream>>>(edge_idx, edge_attr, fill_ptr, csr_dst, csr_ea);
    k_w2t<<<192, 256, 0, stream>>>(enn_W2, W2T);
    k_premlp<<<N_NODES / 4, 256, 0, stream>>>(x, pre_W0, pre_b0, pre_W1, pre_b1,
                                              pre_W2, pre_b2, outA);

    float* cur = outA;
    float* nxt = outB;
    for (int l = 0; l < 3; ++l) {
        k_gemmP<<<dim3(64, 8), 256, 0, stream>>>(cur, W2T + (size_t)l * 64 * 4096, P);
        k_bterm<<<N_NODES / 4, 256, 0, stream>>>(cur, enn_b2 + (size_t)l * 4096, BT, agg);
        k_msg<<<N_NODES / 4, 256, 0, stream>>>(P, BT, csr_off, csr_dst, csr_ea, invdeg,
                                               enn_W1 + l * 64, enn_b1 + l * 64, agg);
        k_gru<<<N_NODES / 4, 256, 0, stream>>>(cur, agg, root_W + l * 4096, conv_b + l * 64,
                                               gru_Wih + l * 64 * 192, gru_Whh + l * 64 * 192,
                                               gru_bih + l * 192, gru_bhh + l * 192, nxt);
        float* tmp = cur; cur = nxt; nxt = tmp;
    }
    k_s2s_post<<<NBATCH, 1024, 0, stream>>>(cur, bstart, bend, s2s_Wih, s2s_Whh, s2s_bih,
                                            s2s_bhh, post_W0, post_b0, post_W1, post_b1,
                                            post_W2, post_b2, post_W3, post_b3, yout);
}

// Round 3
// 403.740 us; speedup vs baseline: 1.1853x; 1.0638x over previous
//
#include <hip/hip_runtime.h>
#include <hip/hip_bf16.h>

#define N_NODES 4096
#define NFEAT   128
#define DIM     64
#define GHID    64
#define NEDGE   32768
#define NBATCH  32

typedef __attribute__((ext_vector_type(8))) short short8;
typedef __attribute__((ext_vector_type(4))) float f4;

__device__ __forceinline__ float sigf(float x) { return 1.0f / (1.0f + __expf(-x)); }

// ---------------- setup kernels ----------------

__global__ __launch_bounds__(256) void k_init(int* cnt_src, int* cnt_dst,
                                              int* bstart, int* bend) {
    int i = blockIdx.x * 256 + threadIdx.x;
    if (i < N_NODES) cnt_src[i] = 0;
    else if (i < 2 * N_NODES) cnt_dst[i - N_NODES] = 0;
    if (i < NBATCH) { bstart[i] = 0x7FFFFFFF; bend[i] = 0; }
}

__global__ void k_count(const int* __restrict__ eidx, const int* __restrict__ bm,
                        int* cnt_src, int* cnt_dst, int* bstart, int* bend) {
    int e = blockIdx.x * 256 + threadIdx.x;
    if (e < NEDGE) {
        atomicAdd(&cnt_src[eidx[e]], 1);
        atomicAdd(&cnt_dst[eidx[NEDGE + e]], 1);
    }
    if (e < N_NODES) {
        int b = bm[e];
        atomicMin(&bstart[b], e);
        atomicMax(&bend[b], e + 1);
    }
}

__global__ __launch_bounds__(1024) void k_scan(const int* __restrict__ cnt_src,
                                               const int* __restrict__ cnt_dst,
                                               int* csr_off, int* fill_ptr, float* invdeg) {
    __shared__ int part[1024];
    int t = threadIdx.x;
    int base = t * 4;
    int v0 = cnt_src[base], v1 = cnt_src[base + 1], v2 = cnt_src[base + 2], v3 = cnt_src[base + 3];
    int mysum = v0 + v1 + v2 + v3;
    part[t] = mysum;
    __syncthreads();
    for (int off = 1; off < 1024; off <<= 1) {
        int x = (t >= off) ? part[t - off] : 0;
        __syncthreads();
        part[t] += x;
        __syncthreads();
    }
    int excl = part[t] - mysum;
    csr_off[base] = excl;     fill_ptr[base] = excl;     excl += v0;
    csr_off[base + 1] = excl; fill_ptr[base + 1] = excl; excl += v1;
    csr_off[base + 2] = excl; fill_ptr[base + 2] = excl; excl += v2;
    csr_off[base + 3] = excl; fill_ptr[base + 3] = excl;
    if (t == 1023) csr_off[N_NODES] = part[1023];
    for (int n = t; n < N_NODES; n += 1024) {
        int d = cnt_dst[n];
        invdeg[n] = 1.0f / (float)(d > 0 ? d : 1);
    }
}

__global__ void k_fill(const int* __restrict__ eidx, const float* __restrict__ ea,
                       int* fill_ptr, int* csr_dst, float* csr_ea) {
    int e = blockIdx.x * 256 + threadIdx.x;
    if (e < NEDGE) {
        int s = eidx[e];
        int pos = atomicAdd(&fill_ptr[s], 1);
        csr_dst[pos] = eidx[NEDGE + e];
        csr_ea[pos] = ea[e];
    }
}

// transpose enn_W2[l][g][k][o] -> W2T[(l*64+g)][o][k] in bf16
__global__ __launch_bounds__(256) void k_w2t(const float* __restrict__ enn_W2,
                                             __hip_bfloat16* __restrict__ W2T) {
    __shared__ __hip_bfloat16 tile[64 * 65];
    size_t base = (size_t)blockIdx.x * 4096;
    int t = threadIdx.x;
    for (int i = t; i < 4096; i += 256) {
        int k = i >> 6, o = i & 63;
        tile[o * 65 + k] = __float2bfloat16(enn_W2[base + i]);
    }
    __syncthreads();
    for (int i = t; i < 4096; i += 256) {
        int o = i >> 6, k = i & 63;
        W2T[base + i] = tile[o * 65 + k];
    }
}

// ---------------- pre-MLP (3 layers fused) ----------------

__global__ __launch_bounds__(256) void k_premlp(const float* __restrict__ x,
        const float* __restrict__ W0, const float* __restrict__ b0,
        const float* __restrict__ W1, const float* __restrict__ b1,
        const float* __restrict__ W2, const float* __restrict__ b2,
        float* __restrict__ out) {
    __shared__ float xr[4][NFEAT];
    __shared__ float ha[4][DIM];
    __shared__ float hb[4][DIM];
    int t = threadIdx.x, w = t >> 6, j = t & 63;
    int n = blockIdx.x * 4 + w;
    xr[w][j] = x[(size_t)n * NFEAT + j];
    xr[w][64 + j] = x[(size_t)n * NFEAT + 64 + j];
    __syncthreads();
    float s = b0[j];
    #pragma unroll 8
    for (int k = 0; k < 128; ++k) s = fmaf(xr[w][k], W0[k * 64 + j], s);
    ha[w][j] = fmaxf(s, 0.f);
    __syncthreads();
    s = b1[j];
    #pragma unroll 8
    for (int k = 0; k < 64; ++k) s = fmaf(ha[w][k], W1[k * 64 + j], s);
    hb[w][j] = fmaxf(s, 0.f);
    __syncthreads();
    s = b2[j];
    #pragma unroll 8
    for (int k = 0; k < 64; ++k) s = fmaf(hb[w][k], W2[k * 64 + j], s);
    out[(size_t)n * 64 + j] = fmaxf(s, 0.f);
}

// ---------------- P = out @ W2 (MFMA bf16) ----------------

__global__ __launch_bounds__(256) void k_gemmP(const float* __restrict__ out,
        const __hip_bfloat16* __restrict__ W2T_l, __hip_bfloat16* __restrict__ P) {
    __shared__ __hip_bfloat16 A[64][72];
    int mtile = blockIdx.x, gchunk = blockIdx.y;
    int t = threadIdx.x;
    const float* Ain = out + (size_t)mtile * 64 * 64;
    for (int i = t; i < 4096; i += 256)
        A[i >> 6][i & 63] = __float2bfloat16(Ain[i]);
    __syncthreads();
    int wave = t >> 6, lane = t & 63;
    int laneM = lane & 15, quad = lane >> 4;
    int arow = wave * 16 + laneM;
    short8 a0 = *(const short8*)&A[arow][quad * 8];
    short8 a1 = *(const short8*)&A[arow][32 + quad * 8];
    #pragma unroll
    for (int gg = 0; gg < 8; ++gg) {
        int g = gchunk * 8 + gg;
        const __hip_bfloat16* Bt = W2T_l + (size_t)g * 4096;  // [o][k]
        #pragma unroll
        for (int sub = 0; sub < 4; ++sub) {
            int o0 = sub * 16;
            short8 b0v = *(const short8*)(Bt + (o0 + laneM) * 64 + quad * 8);
            short8 b1v = *(const short8*)(Bt + (o0 + laneM) * 64 + 32 + quad * 8);
            f4 acc = {0.f, 0.f, 0.f, 0.f};
            acc = __builtin_amdgcn_mfma_f32_16x16x32_bf16(a0, b0v, acc, 0, 0, 0);
            acc = __builtin_amdgcn_mfma_f32_16x16x32_bf16(a1, b1v, acc, 0, 0, 0);
            int rowg = mtile * 64 + wave * 16 + quad * 4;
            int col = g * 64 + o0 + laneM;
            #pragma unroll
            for (int r = 0; r < 4; ++r)
                P[(size_t)(rowg + r) * 4096 + col] = __float2bfloat16(acc[r]);
        }
    }
}

// BT[n][o] = sum_i out[n,i] * b2[i*64+o]; also zero-initializes agg for k_msg
__global__ __launch_bounds__(256) void k_bterm(const float* __restrict__ out,
        const float* __restrict__ b2l, float* __restrict__ BT, float* __restrict__ agg) {
    __shared__ float sh[4][64];
    int t = threadIdx.x, w = t >> 6, j = t & 63;
    int n = blockIdx.x * 4 + w;
    sh[w][j] = out[(size_t)n * 64 + j];
    agg[(size_t)n * 64 + j] = 0.f;
    __syncthreads();
    float s = 0.f;
    #pragma unroll 8
    for (int k = 0; k < 64; ++k) s = fmaf(sh[w][k], b2l[k * 64 + j], s);
    BT[(size_t)n * 64 + j] = s;
}

// ---------------- message + scatter ----------------
#define MSG_CHUNK 128

__global__ __launch_bounds__(256, 2) void k_msg(const __hip_bfloat16* __restrict__ P,
        const float* __restrict__ BT, const int* __restrict__ csr_off,
        const int* __restrict__ csr_dst, const float* __restrict__ csr_ea,
        const float* __restrict__ invdeg, const float* __restrict__ W1l,
        const float* __restrict__ b1l, float* __restrict__ agg) {
    __shared__ float wlds[MSG_CHUNK][64];
    int t = threadIdx.x, wave = t >> 6, lane = t & 63;
    int n0 = blockIdx.x * 4;
    int n = n0 + wave;
    int bs = csr_off[n0], be = csr_off[n0 + 4];
    int ms = csr_off[n], me = csr_off[n + 1];
    float w1v = W1l[lane], b1v = b1l[lane];
    float preg[64];
    const __hip_bfloat16* Pn = P + (size_t)n * 4096;
    #pragma unroll
    for (int g = 0; g < 64; ++g) preg[g] = __bfloat162float(Pn[g * 64 + lane]);
    float bt = BT[(size_t)n * 64 + lane];
    for (int cs = bs; cs < be; cs += MSG_CHUNK) {
        int ccount = be - cs; if (ccount > MSG_CHUNK) ccount = MSG_CHUNK;
        __syncthreads();
        for (int si = wave; si < ccount; si += 4) {
            float ea = csr_ea[cs + si];
            wlds[si][lane] = fmaxf(fmaf(ea, w1v, b1v), 0.f);   // We1 (lane = g)
        }
        __syncthreads();
        int i0 = ms > cs ? ms : cs;
        int i1 = me < cs + ccount ? me : cs + ccount;
        for (int i = i0; i < i1; ++i) {
            int si = i - cs;
            int dst = csr_dst[i];
            float idg = invdeg[dst];
            const float* wr = wlds[si];
            // 4 independent FMA chains (was one 64-deep dependent chain)
            float acc0 = bt, acc1 = 0.f, acc2 = 0.f, acc3 = 0.f;
            #pragma unroll
            for (int g = 0; g < 64; g += 16) {
                float4 w0 = *(const float4*)(wr + g);
                float4 w1 = *(const float4*)(wr + g + 4);
                float4 w2 = *(const float4*)(wr + g + 8);
                float4 w3 = *(const float4*)(wr + g + 12);
                acc0 = fmaf(w0.x, preg[g], acc0);
                acc0 = fmaf(w0.y, preg[g + 1], acc0);
                acc0 = fmaf(w0.z, preg[g + 2], acc0);
                acc0 = fmaf(w0.w, preg[g + 3], acc0);
                acc1 = fmaf(w1.x, preg[g + 4], acc1);
                acc1 = fmaf(w1.y, preg[g + 5], acc1);
                acc1 = fmaf(w1.z, preg[g + 6], acc1);
                acc1 = fmaf(w1.w, preg[g + 7], acc1);
                acc2 = fmaf(w2.x, preg[g + 8], acc2);
                acc2 = fmaf(w2.y, preg[g + 9], acc2);
                acc2 = fmaf(w2.z, preg[g + 10], acc2);
                acc2 = fmaf(w2.w, preg[g + 11], acc2);
                acc3 = fmaf(w3.x, preg[g + 12], acc3);
                acc3 = fmaf(w3.y, preg[g + 13], acc3);
                acc3 = fmaf(w3.z, preg[g + 14], acc3);
                acc3 = fmaf(w3.w, preg[g + 15], acc3);
            }
            float acc = (acc0 + acc1) + (acc2 + acc3);
            atomicAdd(&agg[(size_t)dst * 64 + lane], acc * idg);
        }
    }
}

// ---------------- conv + GRU ----------------

__global__ __launch_bounds__(256) void k_gru(const float* __restrict__ out,
        const float* __restrict__ agg, const float* __restrict__ rootW,
        const float* __restrict__ convb, const float* __restrict__ Wih,
        const float* __restrict__ Whh, const float* __restrict__ bih,
        const float* __restrict__ bhh, float* __restrict__ outn) {
    __shared__ float sh[4][64], sc[4][64];
    int t = threadIdx.x, w = t >> 6, j = t & 63;
    int n = blockIdx.x * 4 + w;
    float hj = out[(size_t)n * 64 + j];
    sh[w][j] = hj;
    __syncthreads();
    float s = agg[(size_t)n * 64 + j] + convb[j];
    #pragma unroll 8
    for (int k = 0; k < 64; ++k) s = fmaf(sh[w][k], rootW[k * 64 + j], s);
    float conv = fmaxf(s, 0.f);
    sc[w][j] = conv;
    __syncthreads();
    float gir = bih[j], giz = bih[64 + j], gin = bih[128 + j];
    float ghr = bhh[j], ghz = bhh[64 + j], ghn = bhh[128 + j];
    #pragma unroll 4
    for (int k = 0; k < 64; ++k) {
        float c = sc[w][k], h = sh[w][k];
        gir = fmaf(c, Wih[k * 192 + j], gir);
        giz = fmaf(c, Wih[k * 192 + 64 + j], giz);
        gin = fmaf(c, Wih[k * 192 + 128 + j], gin);
        ghr = fmaf(h, Whh[k * 192 + j], ghr);
        ghz = fmaf(h, Whh[k * 192 + 64 + j], ghz);
        ghn = fmaf(h, Whh[k * 192 + 128 + j], ghn);
    }
    float r = sigf(gir + ghr);
    float z = sigf(giz + ghz);
    float nn = tanhf(gin + r * ghn);
    outn[(size_t)n * 64 + j] = (1.f - z) * nn + z * hj;
}

// ---------------- Set2Set (3 steps) + post-MLP ----------------
// One 1024-thread block per batch. Node rows cached in LDS (65-pad: conflict-
// free). LSTM weights preloaded to VGPRs once (4 segs x 256 outputs).
#define NCACHE 192

__global__ __launch_bounds__(1024) void k_s2s_post(const float* __restrict__ out,
        const int* __restrict__ bstart, const int* __restrict__ bend,
        const float* __restrict__ Wih, const float* __restrict__ Whh,
        const float* __restrict__ bih, const float* __restrict__ bhh,
        const float* __restrict__ pW0, const float* __restrict__ pb0,
        const float* __restrict__ pW1, const float* __restrict__ pb1,
        const float* __restrict__ pW2, const float* __restrict__ pb2,
        const float* __restrict__ pW3, const float* __restrict__ pb3,
        float* __restrict__ y) {
    __shared__ float cache[NCACHE * 65];   // 48.75 KB node rows
    __shared__ float qs[128], hh[64], cc[64], gates[256];
    __shared__ float ebuf[1024];
    __shared__ float redbuf[1024];         // gate partials [4][256] / rpart [16][64]
    __shared__ float redw[16];
    __shared__ float smax, sinv;
    __shared__ float tmp64[64];
    int t = threadIdx.x, wave = t >> 6, lane = t & 63;
    int b = blockIdx.x;
    int s0 = bstart[b], e0 = bend[b];
    int cnt = e0 - s0;
    if (cnt < 0) cnt = 0;
    if (cnt > 1024) cnt = 1024;
    int ccnt = cnt < NCACHE ? cnt : NCACHE;

    // stage node rows into LDS (coalesced global, padded LDS)
    for (int li = t; li < ccnt * 64; li += 1024) {
        int rowi = li >> 6, d = li & 63;
        cache[rowi * 65 + d] = out[(size_t)(s0 + rowi) * 64 + d];
    }
    // preload LSTM weights to registers: seg 0/1 -> Wih halves, 2/3 -> Whh halves
    int g = t & 255, seg = t >> 8;
    const float* wp;
    int kcnt;
    if (seg == 0)      { wp = Wih + g;             kcnt = 64; }
    else if (seg == 1) { wp = Wih + 64 * 256 + g;  kcnt = 64; }
    else if (seg == 2) { wp = Whh + g;             kcnt = 32; }
    else               { wp = Whh + 32 * 256 + g;  kcnt = 32; }
    float wreg[64];
    #pragma unroll
    for (int j = 0; j < 64; ++j)
        wreg[j] = (j < kcnt) ? wp[(size_t)j * 256] : 0.f;

    if (t < 128) qs[t] = 0.f;
    if (t < 64) { hh[t] = 0.f; cc[t] = 0.f; }
    __syncthreads();

    for (int step = 0; step < 3; ++step) {
        // gates GEMV: each thread = (seg, g) partial over its k-range
        const float* vsrc = (seg == 0) ? qs : (seg == 1) ? qs + 64
                          : (seg == 2) ? hh : hh + 32;
        float partial = 0.f;
        #pragma unroll
        for (int j = 0; j < 64; ++j)
            if (j < kcnt) partial = fmaf(vsrc[j], wreg[j], partial);
        redbuf[seg * 256 + g] = partial;
        __syncthreads();
        if (t < 256)
            gates[t] = bih[t] + bhh[t] + redbuf[t] + redbuf[256 + t]
                     + redbuf[512 + t] + redbuf[768 + t];
        __syncthreads();
        if (t < 64) {
            float cn = sigf(gates[64 + t]) * cc[t] + sigf(gates[t]) * tanhf(gates[128 + t]);
            cc[t] = cn;
            hh[t] = sigf(gates[192 + t]) * tanhf(cn);
        }
        __syncthreads();
        // e[i] = <out_row_i, hh> : one thread per node
        for (int idx = t; idx < cnt; idx += 1024) {
            float s = 0.f;
            if (idx < NCACHE) {
                const float* row = cache + idx * 65;
                #pragma unroll 8
                for (int d = 0; d < 64; ++d) s = fmaf(row[d], hh[d], s);
            } else {
                const float* row = out + (size_t)(s0 + idx) * 64;
                for (int d = 0; d < 64; ++d) s = fmaf(row[d], hh[d], s);
            }
            ebuf[idx] = s;
        }
        __syncthreads();
        // max
        float lm = (t < cnt) ? ebuf[t] : -3.0e38f;
        #pragma unroll
        for (int off = 32; off > 0; off >>= 1) lm = fmaxf(lm, __shfl_down(lm, off, 64));
        if (lane == 0) redw[wave] = lm;
        __syncthreads();
        if (t == 0) {
            float m = redw[0];
            #pragma unroll
            for (int w2 = 1; w2 < 16; ++w2) m = fmaxf(m, redw[w2]);
            smax = m;
        }
        __syncthreads();
        float m = smax;
        float av = 0.f;
        if (t < cnt) {
            av = __expf(ebuf[t] - m);
            ebuf[t] = av;
        }
        float ls = av;
        #pragma unroll
        for (int off = 32; off > 0; off >>= 1) ls += __shfl_down(ls, off, 64);
        if (lane == 0) redw[wave] = ls;
        __syncthreads();
        if (t == 0) {
            float s = 0.f;
            #pragma unroll
            for (int w2 = 0; w2 < 16; ++w2) s += redw[w2];
            sinv = (cnt > 0) ? 1.f / s : 0.f;
        }
        __syncthreads();
        float inv = sinv;
        // r_read: wave = segment, lane = dim
        float r = 0.f;
        for (int idx = wave; idx < cnt; idx += 16) {
            float a = ebuf[idx];
            float v = (idx < NCACHE) ? cache[idx * 65 + lane]
                                     : out[(size_t)(s0 + idx) * 64 + lane];
            r = fmaf(a, v, r);
        }
        redbuf[wave * 64 + lane] = r;
        __syncthreads();
        if (t < 64) {
            float s = 0.f;
            #pragma unroll
            for (int w2 = 0; w2 < 16; ++w2) s += redbuf[w2 * 64 + t];
            qs[64 + t] = s * inv;
            qs[t] = hh[t];
        }
        __syncthreads();
    }
    // post-MLP
    if (t < 64) {
        float s = pb0[t];
        #pragma unroll 4
        for (int k = 0; k < 128; ++k) s = fmaf(qs[k], pW0[k * 64 + t], s);
        tmp64[t] = fmaxf(s, 0.f);
    }
    __syncthreads();
    float h1v = 0.f;
    if (t < 64) {
        float s = pb1[t];
        #pragma unroll 4
        for (int k = 0; k < 64; ++k) s = fmaf(tmp64[k], pW1[k * 64 + t], s);
        h1v = fmaxf(s, 0.f);
    }
    __syncthreads();
    if (t < 64) tmp64[t] = h1v;
    __syncthreads();
    if (t < 64) {
        float s = pb2[t];
        #pragma unroll 4
        for (int k = 0; k < 64; ++k) s = fmaf(tmp64[k], pW2[k * 64 + t], s);
        gates[t] = fmaxf(s, 0.f) * pW3[t];
    }
    __syncthreads();
    if (t == 0) {
        float yy = pb3[0];
        for (int k = 0; k < 64; ++k) yy += gates[k];
        y[b] = yy;
    }
}

// ---------------- host ----------------

extern "C" void kernel_launch(void* const* d_in, const int* in_sizes, int n_in,
                              void* d_out, int out_size, void* d_ws, size_t ws_size,
                              hipStream_t stream) {
    const float* x         = (const float*)d_in[0];
    const float* edge_attr = (const float*)d_in[1];
    const int*   edge_idx  = (const int*)d_in[2];
    const int*   batch_map = (const int*)d_in[3];
    const float* pre_W0 = (const float*)d_in[4];
    const float* pre_b0 = (const float*)d_in[5];
    const float* pre_W1 = (const float*)d_in[6];
    const float* pre_b1 = (const float*)d_in[7];
    const float* pre_W2 = (const float*)d_in[8];
    const float* pre_b2 = (const float*)d_in[9];
    const float* enn_W1 = (const float*)d_in[10];
    const float* enn_b1 = (const float*)d_in[11];
    const float* enn_W2 = (const float*)d_in[12];
    const float* enn_b2 = (const float*)d_in[13];
    const float* root_W = (const float*)d_in[14];
    const float* conv_b = (const float*)d_in[15];
    const float* gru_Wih = (const float*)d_in[16];
    const float* gru_Whh = (const float*)d_in[17];
    const float* gru_bih = (const float*)d_in[18];
    const float* gru_bhh = (const float*)d_in[19];
    const float* s2s_Wih = (const float*)d_in[20];
    const float* s2s_Whh = (const float*)d_in[21];
    const float* s2s_bih = (const float*)d_in[22];
    const float* s2s_bhh = (const float*)d_in[23];
    const float* post_W0 = (const float*)d_in[24];
    const float* post_b0 = (const float*)d_in[25];
    const float* post_W1 = (const float*)d_in[26];
    const float* post_b1 = (const float*)d_in[27];
    const float* post_W2 = (const float*)d_in[28];
    const float* post_b2 = (const float*)d_in[29];
    const float* post_W3 = (const float*)d_in[30];
    const float* post_b3 = (const float*)d_in[31];
    float* yout = (float*)d_out;

    char* p = (char*)d_ws;
    auto take = [&](size_t bytes) -> char* {
        char* r = p;
        p += (bytes + 255) & ~(size_t)255;
        return r;
    };
    float* outA = (float*)take((size_t)N_NODES * 64 * 4);
    float* outB = (float*)take((size_t)N_NODES * 64 * 4);
    __hip_bfloat16* P = (__hip_bfloat16*)take((size_t)N_NODES * 4096 * 2);
    float* BT  = (float*)take((size_t)N_NODES * 64 * 4);
    float* agg = (float*)take((size_t)N_NODES * 64 * 4);
    __hip_bfloat16* W2T = (__hip_bfloat16*)take((size_t)3 * 64 * 4096 * 2);
    int* csr_off  = (int*)take((size_t)(N_NODES + 1) * 4);
    int* fill_ptr = (int*)take((size_t)N_NODES * 4);
    int* cnt_src  = (int*)take((size_t)N_NODES * 4);
    int* cnt_dst  = (int*)take((size_t)N_NODES * 4);
    float* invdeg = (float*)take((size_t)N_NODES * 4);
    int* csr_dst  = (int*)take((size_t)NEDGE * 4);
    float* csr_ea = (float*)take((size_t)NEDGE * 4);
    int* bstart   = (int*)take((size_t)NBATCH * 4);
    int* bend     = (int*)take((size_t)NBATCH * 4);

    k_init<<<(2 * N_NODES) / 256, 256, 0, stream>>>(cnt_src, cnt_dst, bstart, bend);
    k_count<<<NEDGE / 256, 256, 0, stream>>>(edge_idx, batch_map, cnt_src, cnt_dst,
                                             bstart, bend);
    k_scan<<<1, 1024, 0, stream>>>(cnt_src, cnt_dst, csr_off, fill_ptr, invdeg);
    k_fill<<<NEDGE / 256, 256, 0, stream>>>(edge_idx, edge_attr, fill_ptr, csr_dst, csr_ea);
    k_w2t<<<192, 256, 0, stream>>>(enn_W2, W2T);
    k_premlp<<<N_NODES / 4, 256, 0, stream>>>(x, pre_W0, pre_b0, pre_W1, pre_b1,
                                              pre_W2, pre_b2, outA);

    float* cur = outA;
    float* nxt = outB;
    for (int l = 0; l < 3; ++l) {
        k_gemmP<<<dim3(64, 8), 256, 0, stream>>>(cur, W2T + (size_t)l * 64 * 4096, P);
        k_bterm<<<N_NODES / 4, 256, 0, stream>>>(cur, enn_b2 + (size_t)l * 4096, BT, agg);
        k_msg<<<N_NODES / 4, 256, 0, stream>>>(P, BT, csr_off, csr_dst, csr_ea, invdeg,
                                               enn_W1 + l * 64, enn_b1 + l * 64, agg);
        k_gru<<<N_NODES / 4, 256, 0, stream>>>(cur, agg, root_W + l * 4096, conv_b + l * 64,
                                               gru_Wih + l * 64 * 192, gru_Whh + l * 64 * 192,
                                               gru_bih + l * 192, gru_bhh + l * 192, nxt);
        float* tmp = cur; cur = nxt; nxt = tmp;
    }
    k_s2s_post<<<NBATCH, 1024, 0, stream>>>(cur, bstart, bend, s2s_Wih, s2s_Whh, s2s_bih,
                                            s2s_bhh, post_W0, post_b0, post_W1, post_b1,
                                            post_W2, post_b2, post_W3, post_b3, yout);
}